// Round 2
// baseline (2325.389 us; speedup 1.0000x reference)
//
#include <hip/hip_runtime.h>
#include <hip/hip_bf16.h>

#define NN 100000
#define EE 1600000

typedef __hip_bfloat16 bf16_t;

// ---- workspace layout (float offsets) ----
#define FX    0            // x_cont fp32            600000
#define PARB  600000       // params fp32            4465
#define EMB   604480       // N*32                   3200000
#define PBUF  3804480      // N*32
#define QBUF  7004480      // N*32
#define ABUF  10204480     // N*32 (u32-encoded during k_edge)
#define SOFF  13404480     // stats + small scratch

// ---- param offsets inside PARB ----
#define O_WCONT 0
#define O_BCONT 96
#define O_TCHRG 112
#define O_TPDG  136
#define O_TPV   192
#define O_WCAT  256
#define O_BCAT  640
#define O_WENC  656
#define O_BENC  1680
#define O_GALL  1712
#define O_BEALL 1744
#define O_WMSG  1776
#define O_BMSG  3824
#define O_GCONV 3856
#define O_BECONV 3888
#define O_WOUT1 3920
#define O_BOUT1 4432
#define O_WOUT2 4448
#define O_BOUT2 4464
#define NPAR    4465

__device__ __forceinline__ float bf(unsigned short u) {
    return __uint_as_float(((unsigned)u) << 16);
}
__device__ __forceinline__ float elu(float x) {
    return x > 0.0f ? x : expm1f(x);
}
// order-preserving float->uint encoding; 0 is unreachable (sentinel for "no edge")
__device__ __forceinline__ unsigned enc(float f) {
    unsigned b = __float_as_uint(f);
    return b ^ ((unsigned)((int)b >> 31) | 0x80000000u);
}
__device__ __forceinline__ float dec(unsigned u) {
    unsigned b = (u & 0x80000000u) ? (u ^ 0x80000000u) : ~u;
    return __uint_as_float(b);
}

// ---------------- dtype detection ----------------
// Read W_enc (1024 logical elements) as bf16. If data is really float32, the
// low halves of the floats appear as random-exponent bf16 garbage -> huge.
__global__ __launch_bounds__(64) void k_detect(const unsigned short* __restrict__ w,
                                               int* __restrict__ flag)
{
    int bad = 0;
    for (int i = threadIdx.x; i < 1024; i += 64) {
        unsigned e = (w[i] >> 7) & 0xFFu;   // bf16 exponent field
        if (e >= 137u) bad = 1;             // |v| >= 2^10 -> impossible for real weights
    }
    if (bad) atomicOr(flag, 1);
}

// ---------------- convert all float tensors to fp32 workspace ----------------
struct ConvArgs {
    const void* xc;
    const void* p[19];
    const int*  flag;
    float*      fx;
    float*      par;
};

__global__ __launch_bounds__(256) void k_convert(ConvArgs a)
{
    const int offs[20] = {O_WCONT,O_BCONT,O_TCHRG,O_TPDG,O_TPV,O_WCAT,O_BCAT,O_WENC,
                          O_BENC,O_GALL,O_BEALL,O_WMSG,O_BMSG,O_GCONV,O_BECONV,
                          O_WOUT1,O_BOUT1,O_WOUT2,O_BOUT2,NPAR};
    int f32 = *a.flag;
    int b = blockIdx.x, tid = threadIdx.x;
    if (b < 586) {
        int i0 = b * 1024;
        int lim = i0 + 1024; if (lim > 600000) lim = 600000;
        for (int i = i0 + tid; i < lim; i += 256)
            a.fx[i] = f32 ? ((const float*)a.xc)[i] : bf(((const unsigned short*)a.xc)[i]);
    } else {
        for (int i = tid; i < NPAR; i += 256) {
            int t = 0;
            while (offs[t + 1] <= i) t++;
            int l = i - offs[t];
            const void* s = a.p[t];
            a.par[i] = f32 ? ((const float*)s)[l] : bf(((const unsigned short*)s)[l]);
        }
    }
}

// ---------------- node embedding (pre-batchnorm) ----------------
__global__ __launch_bounds__(256) void k_embed(
    const float* __restrict__ fx, const int* __restrict__ x_cat,
    const float* __restrict__ par, float* __restrict__ emb)
{
    __shared__ float sWc[96], sbc[16], sTc[24], sTp[56], sTv[64];
    __shared__ float sWcat[384], sbcat[16], sWe[1024], sbe[32];
    int tid = threadIdx.x;
    for (int i = tid; i < 96;   i += 256) sWc[i]   = par[O_WCONT + i];
    for (int i = tid; i < 16;   i += 256) sbc[i]   = par[O_BCONT + i];
    for (int i = tid; i < 24;   i += 256) sTc[i]   = par[O_TCHRG + i];
    for (int i = tid; i < 56;   i += 256) sTp[i]   = par[O_TPDG + i];
    for (int i = tid; i < 64;   i += 256) sTv[i]   = par[O_TPV + i];
    for (int i = tid; i < 384;  i += 256) sWcat[i] = par[O_WCAT + i];
    for (int i = tid; i < 16;   i += 256) sbcat[i] = par[O_BCAT + i];
    for (int i = tid; i < 1024; i += 256) sWe[i]   = par[O_WENC + i];
    for (int i = tid; i < 32;   i += 256) sbe[i]   = par[O_BENC + i];
    __syncthreads();

    int n = blockIdx.x * 256 + tid;
    if (n >= NN) return;

    const float* xr = fx + (size_t)n * 6;
    float x[6];
    #pragma unroll
    for (int k = 0; k < 6; k++) x[k] = xr[k];

    float ec[16];
    #pragma unroll
    for (int j = 0; j < 16; j++) {
        float a = sbc[j];
        #pragma unroll
        for (int k = 0; k < 6; k++) a += x[k] * sWc[k*16 + j];
        ec[j] = elu(a);
    }

    int c0 = x_cat[n*3+0], c1 = x_cat[n*3+1], c2 = x_cat[n*3+2];
    int a0 = c0 < 0 ? -c0 : c0;
    int pi = (a0==1)?0:(a0==2)?1:(a0==11)?2:(a0==13)?3:(a0==22)?4:(a0==130)?5:6;
    int ci_idx = c1 + 1;
    int vi = c2;

    float cin[24];
    #pragma unroll
    for (int k = 0; k < 8; k++) {
        cin[k]      = sTc[ci_idx*8 + k];
        cin[8 + k]  = sTp[pi*8 + k];
        cin[16 + k] = sTv[vi*8 + k];
    }
    float ecat[16];
    #pragma unroll
    for (int j = 0; j < 16; j++) {
        float a = sbcat[j];
        #pragma unroll
        for (int k = 0; k < 24; k++) a += cin[k] * sWcat[k*16 + j];
        ecat[j] = elu(a);
    }

    float in32[32];
    #pragma unroll
    for (int k = 0; k < 16; k++) { in32[k] = ecat[k]; in32[16 + k] = ec[k]; }

    float er[32];
    #pragma unroll
    for (int j = 0; j < 32; j++) {
        float a = sbe[j];
        #pragma unroll
        for (int k = 0; k < 32; k++) a += in32[k] * sWe[k*32 + j];
        er[j] = elu(a);
    }

    float4* o = (float4*)(emb + (size_t)n * 32);
    #pragma unroll
    for (int g = 0; g < 8; g++)
        o[g] = make_float4(er[g*4], er[g*4+1], er[g*4+2], er[g*4+3]);
}

// ---------------- stats: per-channel sum & sumsq over (N,32) ----------------
__global__ __launch_bounds__(256) void k_stats(const float* __restrict__ xin,
                                               float* __restrict__ outsums, int count)
{
    __shared__ float ls[64];
    int tid = threadIdx.x;
    if (tid < 64) ls[tid] = 0.0f;
    __syncthreads();
    int idx = blockIdx.x * 256 + tid;
    int stride = gridDim.x * 256;
    int c = idx & 31;
    float s = 0.0f, q = 0.0f;
    for (int i = idx; i < count; i += stride) {
        float v = xin[i];
        s += v; q += v * v;
    }
    s += __shfl_xor(s, 32);
    q += __shfl_xor(q, 32);
    if ((tid & 63) < 32) {
        atomicAdd(&ls[c], s);
        atomicAdd(&ls[32 + c], q);
    }
    __syncthreads();
    if (tid < 64) atomicAdd(&outsums[tid], ls[tid]);
}

// ---------------- prep1: bn1 scale/shift + folded P/Q weights ----------------
__global__ __launch_bounds__(256) void k_prep1(
    const float* __restrict__ par, const float* __restrict__ stats,
    float* __restrict__ scale1, float* __restrict__ shift1,
    float* __restrict__ WP, float* __restrict__ WQ,
    float* __restrict__ bP, float* __restrict__ bQ)
{
    __shared__ float ssc[32], ssh[32];
    int tid = threadIdx.x;
    if (tid < 32) {
        float mu  = stats[tid] * (1.0f / NN);
        float var = stats[32 + tid] * (1.0f / NN) - mu * mu;
        float s   = par[O_GALL + tid] * rsqrtf(var + 1e-5f);
        float sh  = par[O_BEALL + tid] - mu * s;
        ssc[tid] = s; ssh[tid] = sh;
        scale1[tid] = s; shift1[tid] = sh;
    }
    __syncthreads();
    for (int e = tid; e < 1024; e += 256) {
        int k = e >> 5;
        float w1 = par[O_WMSG + e];
        float w2 = par[O_WMSG + 1024 + e];
        WP[e] = ssc[k] * (w1 - w2);
        WQ[e] = ssc[k] * w2;
    }
    if (tid < 32) {
        float aP = par[O_BMSG + tid], aQ = 0.0f;
        for (int k = 0; k < 32; k++) {
            float w1 = par[O_WMSG + k*32 + tid];
            float w2 = par[O_WMSG + (k+32)*32 + tid];
            aP += ssh[k] * (w1 - w2);
            aQ += ssh[k] * w2;
        }
        bP[tid] = aP; bQ[tid] = aQ;
    }
}

// ---------------- normalized emb + P' and Q per node ----------------
__global__ __launch_bounds__(256) void k_pq(
    const float* __restrict__ scale1, const float* __restrict__ shift1,
    const float* __restrict__ WP, const float* __restrict__ WQ,
    const float* __restrict__ bP, const float* __restrict__ bQ,
    float* __restrict__ emb, float* __restrict__ P, float* __restrict__ Q)
{
    __shared__ float sWP[1024], sWQ[1024], sbP[32], sbQ[32], ssc[32], ssh[32];
    int tid = threadIdx.x;
    for (int i = tid; i < 1024; i += 256) { sWP[i] = WP[i]; sWQ[i] = WQ[i]; }
    if (tid < 32) { sbP[tid] = bP[tid]; sbQ[tid] = bQ[tid]; ssc[tid] = scale1[tid]; ssh[tid] = shift1[tid]; }
    __syncthreads();

    int n = blockIdx.x * 256 + tid;
    if (n >= NN) return;

    float e[32];
    float4* er = (float4*)(emb + (size_t)n * 32);
    #pragma unroll
    for (int g = 0; g < 8; g++) {
        float4 v = er[g];
        e[g*4+0] = v.x; e[g*4+1] = v.y; e[g*4+2] = v.z; e[g*4+3] = v.w;
    }
    #pragma unroll
    for (int g = 0; g < 8; g++) {
        float4 v;
        v.x = e[g*4+0]*ssc[g*4+0] + ssh[g*4+0];
        v.y = e[g*4+1]*ssc[g*4+1] + ssh[g*4+1];
        v.z = e[g*4+2]*ssc[g*4+2] + ssh[g*4+2];
        v.w = e[g*4+3]*ssc[g*4+3] + ssh[g*4+3];
        er[g] = v;
    }
    float4* pr = (float4*)(P + (size_t)n * 32);
    float4* qr = (float4*)(Q + (size_t)n * 32);
    #pragma unroll
    for (int cg = 0; cg < 8; cg++) {
        float4 aP = *(const float4*)&sbP[cg*4];
        float4 aQ = *(const float4*)&sbQ[cg*4];
        #pragma unroll
        for (int k = 0; k < 32; k++) {
            float ek = e[k];
            float4 wp = *(const float4*)&sWP[k*32 + cg*4];
            float4 wq = *(const float4*)&sWQ[k*32 + cg*4];
            aP.x += ek * wp.x; aP.y += ek * wp.y; aP.z += ek * wp.z; aP.w += ek * wp.w;
            aQ.x += ek * wq.x; aQ.y += ek * wq.y; aQ.z += ek * wq.z; aQ.w += ek * wq.w;
        }
        pr[cg] = aP;
        qr[cg] = aQ;
    }
}

// ---------------- edge scatter-max (encoded u32 atomics) ----------------
__global__ __launch_bounds__(256) void k_edge(
    const int* __restrict__ edge_index, const float* __restrict__ Q,
    unsigned int* __restrict__ agg)
{
    int e = blockIdx.x * 256 + threadIdx.x;
    if (e >= EE) return;
    int s = edge_index[e];
    int d = edge_index[EE + e];
    const float4* q = (const float4*)(Q + (size_t)s * 32);
    unsigned int* a = agg + (size_t)d * 32;
    #pragma unroll
    for (int g = 0; g < 8; g++) {
        float4 v = q[g];
        atomicMax(a + g*4 + 0, enc(v.x));
        atomicMax(a + g*4 + 1, enc(v.y));
        atomicMax(a + g*4 + 2, enc(v.z));
        atomicMax(a + g*4 + 3, enc(v.w));
    }
}

// ---------------- decode agg: agg = (has edge) ? P' + max(Q[src]) : 0 ----------------
__global__ __launch_bounds__(256) void k_agg(const float* __restrict__ P, float* __restrict__ agg)
{
    int n = blockIdx.x * 256 + threadIdx.x;
    if (n >= NN) return;
    const float4* pr = (const float4*)(P + (size_t)n * 32);
    uint4* ar = (uint4*)((unsigned*)agg + (size_t)n * 32);
    #pragma unroll
    for (int g = 0; g < 8; g++) {
        uint4 u = ar[g];
        float4 p = pr[g];
        float4 o;
        o.x = u.x ? dec(u.x) + p.x : 0.0f;
        o.y = u.y ? dec(u.y) + p.y : 0.0f;
        o.z = u.z ? dec(u.z) + p.z : 0.0f;
        o.w = u.w ? dec(u.w) + p.w : 0.0f;
        ((float4*)ar)[g] = o;
    }
}

// ---------------- prep2: bn2 scale/shift ----------------
__global__ __launch_bounds__(64) void k_prep2(
    const float* __restrict__ par, const float* __restrict__ stats2,
    float* __restrict__ scale2, float* __restrict__ shift2)
{
    int c = threadIdx.x;
    if (c >= 32) return;
    float mu  = stats2[c] * (1.0f / NN);
    float var = stats2[32 + c] * (1.0f / NN) - mu * mu;
    float s   = par[O_GCONV + c] * rsqrtf(var + 1e-5f);
    scale2[c] = s;
    shift2[c] = par[O_BECONV + c] - mu * s;
}

// ---------------- output MLP ----------------
__global__ __launch_bounds__(256) void k_out(
    const float* __restrict__ emb, const float* __restrict__ agg,
    const float* __restrict__ scale2, const float* __restrict__ shift2,
    const float* __restrict__ par, const int* __restrict__ flag,
    void* __restrict__ out)
{
    __shared__ float sW1[512], sb1[16], sW2[16], ssc[32], ssh[32];
    __shared__ float sb2;
    int tid = threadIdx.x;
    for (int i = tid; i < 512; i += 256) sW1[i] = par[O_WOUT1 + i];
    if (tid < 16) { sb1[tid] = par[O_BOUT1 + tid]; sW2[tid] = par[O_WOUT2 + tid]; }
    if (tid < 32) { ssc[tid] = scale2[tid]; ssh[tid] = shift2[tid]; }
    if (tid == 0) sb2 = par[O_BOUT2];
    __syncthreads();

    int n = blockIdx.x * 256 + tid;
    if (n >= NN) return;

    const float4* er = (const float4*)(emb + (size_t)n * 32);
    const float4* ar = (const float4*)(agg + (size_t)n * 32);
    float h[32];
    #pragma unroll
    for (int g = 0; g < 8; g++) {
        float4 ev = er[g];
        float4 av = ar[g];
        h[g*4+0] = ev.x + av.x * ssc[g*4+0] + ssh[g*4+0];
        h[g*4+1] = ev.y + av.y * ssc[g*4+1] + ssh[g*4+1];
        h[g*4+2] = ev.z + av.z * ssc[g*4+2] + ssh[g*4+2];
        h[g*4+3] = ev.w + av.w * ssc[g*4+3] + ssh[g*4+3];
    }
    float o1[16];
    #pragma unroll
    for (int j = 0; j < 16; j++) {
        float a = sb1[j];
        #pragma unroll
        for (int k = 0; k < 32; k++) a += h[k] * sW1[k*16 + j];
        o1[j] = elu(a);
    }
    float acc = sb2;
    #pragma unroll
    for (int j = 0; j < 16; j++) acc += o1[j] * sW2[j];

    if (*flag) ((float*)out)[n] = acc;
    else       ((bf16_t*)out)[n] = __float2bfloat16(acc);
}

extern "C" void kernel_launch(void* const* d_in, const int* in_sizes, int n_in,
                              void* d_out, int out_size, void* d_ws, size_t ws_size,
                              hipStream_t stream)
{
    const int* x_cat = (const int*)d_in[1];
    const int* eidx  = (const int*)d_in[2];

    float* ws     = (float*)d_ws;
    float* fx     = ws + FX;
    float* par    = ws + PARB;
    float* emb    = ws + EMB;
    float* P      = ws + PBUF;
    float* Q      = ws + QBUF;
    float* agg    = ws + ABUF;
    float* stats  = ws + SOFF;            // [0:32) sum1 [32:64) sq1 [64:96) sum2 [96:128) sq2
    float* scale1 = stats + 128;
    float* shift1 = stats + 160;
    float* scale2 = stats + 192;
    float* shift2 = stats + 224;
    float* WP     = stats + 256;          // 1024
    float* WQ     = stats + 1280;         // 1024
    float* bP     = stats + 2304;         // 32
    float* bQ     = stats + 2336;         // 32
    int*   flag   = (int*)(stats + 2368);

    hipMemsetAsync(stats, 0, 2376 * sizeof(float), stream);
    hipMemsetAsync(agg, 0, (size_t)NN * 32 * sizeof(float), stream);

    k_detect<<<1, 64, 0, stream>>>((const unsigned short*)d_in[11], flag);

    ConvArgs ca;
    ca.xc = d_in[0];
    for (int t = 0; t < 19; t++) ca.p[t] = d_in[4 + t];
    ca.flag = flag; ca.fx = fx; ca.par = par;
    k_convert<<<587, 256, 0, stream>>>(ca);

    int nb = (NN + 255) / 256;  // 391
    k_embed<<<nb, 256, 0, stream>>>(fx, x_cat, par, emb);
    k_stats<<<512, 256, 0, stream>>>(emb, stats, NN * 32);
    k_prep1<<<1, 256, 0, stream>>>(par, stats, scale1, shift1, WP, WQ, bP, bQ);
    k_pq<<<nb, 256, 0, stream>>>(scale1, shift1, WP, WQ, bP, bQ, emb, P, Q);
    k_edge<<<EE / 256, 256, 0, stream>>>(eidx, Q, (unsigned int*)agg);
    k_agg<<<nb, 256, 0, stream>>>(P, agg);
    k_stats<<<512, 256, 0, stream>>>(agg, stats + 64, NN * 32);
    k_prep2<<<1, 64, 0, stream>>>(par, stats + 64, scale2, shift2);
    k_out<<<nb, 256, 0, stream>>>(emb, agg, scale2, shift2, par, flag, d_out);
}

// Round 3
// 480.495 us; speedup vs baseline: 4.8396x; 4.8396x over previous
//
#include <hip/hip_runtime.h>
#include <hip/hip_bf16.h>

#define NN 100000
#define EE 1600000
#define NB_SCAN 391   // ceil(NN/256)

typedef __hip_bfloat16 bf16_t;

// ---- workspace layout (float offsets) ----
#define FX    0            // x_cont fp32            600000
#define PARB  600000       // params fp32            4465
#define EMB   604480       // N*32
#define PBUF  3804480      // N*32
#define QBUF  7004480      // N*32
#define ABUF  10204480     // N*32
#define SOFF  13404480     // stats + small scratch (4096)
#define DEG   (SOFF + 4096)          // 100000 ints
#define ROWP  (DEG + 100000)         // 100001 ints
#define CURS  (ROWP + 100002)        // 100000 ints
#define BSUM  (CURS + 100000)        // 512 ints
#define SRCL  (BSUM + 512)           // 1600000 ints

// ---- param offsets inside PARB ----
#define O_WCONT 0
#define O_BCONT 96
#define O_TCHRG 112
#define O_TPDG  136
#define O_TPV   192
#define O_WCAT  256
#define O_BCAT  640
#define O_WENC  656
#define O_BENC  1680
#define O_GALL  1712
#define O_BEALL 1744
#define O_WMSG  1776
#define O_BMSG  3824
#define O_GCONV 3856
#define O_BECONV 3888
#define O_WOUT1 3920
#define O_BOUT1 4432
#define O_WOUT2 4448
#define O_BOUT2 4464
#define NPAR    4465

__device__ __forceinline__ float bf(unsigned short u) {
    return __uint_as_float(((unsigned)u) << 16);
}
__device__ __forceinline__ float elu(float x) {
    return x > 0.0f ? x : expm1f(x);
}

// ---------------- dtype detection (bf16 vs f32 tensors) ----------------
__global__ __launch_bounds__(64) void k_detect(const unsigned short* __restrict__ w,
                                               int* __restrict__ flag)
{
    int bad = 0;
    for (int i = threadIdx.x; i < 1024; i += 64) {
        unsigned e = (w[i] >> 7) & 0xFFu;
        if (e >= 137u) bad = 1;
    }
    if (bad) atomicOr(flag, 1);
}

// ---------------- convert all float tensors to fp32 workspace ----------------
struct ConvArgs {
    const void* xc;
    const void* p[19];
    const int*  flag;
    float*      fx;
    float*      par;
};

__global__ __launch_bounds__(256) void k_convert(ConvArgs a)
{
    const int offs[20] = {O_WCONT,O_BCONT,O_TCHRG,O_TPDG,O_TPV,O_WCAT,O_BCAT,O_WENC,
                          O_BENC,O_GALL,O_BEALL,O_WMSG,O_BMSG,O_GCONV,O_BECONV,
                          O_WOUT1,O_BOUT1,O_WOUT2,O_BOUT2,NPAR};
    int f32 = *a.flag;
    int b = blockIdx.x, tid = threadIdx.x;
    if (b < 586) {
        int i0 = b * 1024;
        int lim = i0 + 1024; if (lim > 600000) lim = 600000;
        for (int i = i0 + tid; i < lim; i += 256)
            a.fx[i] = f32 ? ((const float*)a.xc)[i] : bf(((const unsigned short*)a.xc)[i]);
    } else {
        for (int i = tid; i < NPAR; i += 256) {
            int t = 0;
            while (offs[t + 1] <= i) t++;
            int l = i - offs[t];
            const void* s = a.p[t];
            a.par[i] = f32 ? ((const float*)s)[l] : bf(((const unsigned short*)s)[l]);
        }
    }
}

// ---------------- node embedding (pre-batchnorm) ----------------
__global__ __launch_bounds__(256) void k_embed(
    const float* __restrict__ fx, const int* __restrict__ x_cat,
    const float* __restrict__ par, float* __restrict__ emb)
{
    __shared__ float sWc[96], sbc[16], sTc[24], sTp[56], sTv[64];
    __shared__ float sWcat[384], sbcat[16], sWe[1024], sbe[32];
    int tid = threadIdx.x;
    for (int i = tid; i < 96;   i += 256) sWc[i]   = par[O_WCONT + i];
    for (int i = tid; i < 16;   i += 256) sbc[i]   = par[O_BCONT + i];
    for (int i = tid; i < 24;   i += 256) sTc[i]   = par[O_TCHRG + i];
    for (int i = tid; i < 56;   i += 256) sTp[i]   = par[O_TPDG + i];
    for (int i = tid; i < 64;   i += 256) sTv[i]   = par[O_TPV + i];
    for (int i = tid; i < 384;  i += 256) sWcat[i] = par[O_WCAT + i];
    for (int i = tid; i < 16;   i += 256) sbcat[i] = par[O_BCAT + i];
    for (int i = tid; i < 1024; i += 256) sWe[i]   = par[O_WENC + i];
    for (int i = tid; i < 32;   i += 256) sbe[i]   = par[O_BENC + i];
    __syncthreads();

    int n = blockIdx.x * 256 + tid;
    if (n >= NN) return;

    const float* xr = fx + (size_t)n * 6;
    float x[6];
    #pragma unroll
    for (int k = 0; k < 6; k++) x[k] = xr[k];

    float ec[16];
    #pragma unroll
    for (int j = 0; j < 16; j++) {
        float a = sbc[j];
        #pragma unroll
        for (int k = 0; k < 6; k++) a += x[k] * sWc[k*16 + j];
        ec[j] = elu(a);
    }

    int c0 = x_cat[n*3+0], c1 = x_cat[n*3+1], c2 = x_cat[n*3+2];
    int a0 = c0 < 0 ? -c0 : c0;
    int pi = (a0==1)?0:(a0==2)?1:(a0==11)?2:(a0==13)?3:(a0==22)?4:(a0==130)?5:6;
    int ci_idx = c1 + 1;
    int vi = c2;

    float cin[24];
    #pragma unroll
    for (int k = 0; k < 8; k++) {
        cin[k]      = sTc[ci_idx*8 + k];
        cin[8 + k]  = sTp[pi*8 + k];
        cin[16 + k] = sTv[vi*8 + k];
    }
    float ecat[16];
    #pragma unroll
    for (int j = 0; j < 16; j++) {
        float a = sbcat[j];
        #pragma unroll
        for (int k = 0; k < 24; k++) a += cin[k] * sWcat[k*16 + j];
        ecat[j] = elu(a);
    }

    float in32[32];
    #pragma unroll
    for (int k = 0; k < 16; k++) { in32[k] = ecat[k]; in32[16 + k] = ec[k]; }

    float er[32];
    #pragma unroll
    for (int j = 0; j < 32; j++) {
        float a = sbe[j];
        #pragma unroll
        for (int k = 0; k < 32; k++) a += in32[k] * sWe[k*32 + j];
        er[j] = elu(a);
    }

    float4* o = (float4*)(emb + (size_t)n * 32);
    #pragma unroll
    for (int g = 0; g < 8; g++)
        o[g] = make_float4(er[g*4], er[g*4+1], er[g*4+2], er[g*4+3]);
}

// ---------------- stats: per-channel sum & sumsq over (N,32) ----------------
__global__ __launch_bounds__(256) void k_stats(const float* __restrict__ xin,
                                               float* __restrict__ outsums, int count)
{
    __shared__ float ls[64];
    int tid = threadIdx.x;
    if (tid < 64) ls[tid] = 0.0f;
    __syncthreads();
    int idx = blockIdx.x * 256 + tid;
    int stride = gridDim.x * 256;
    int c = idx & 31;
    float s = 0.0f, q = 0.0f;
    for (int i = idx; i < count; i += stride) {
        float v = xin[i];
        s += v; q += v * v;
    }
    s += __shfl_xor(s, 32);
    q += __shfl_xor(q, 32);
    if ((tid & 63) < 32) {
        atomicAdd(&ls[c], s);
        atomicAdd(&ls[32 + c], q);
    }
    __syncthreads();
    if (tid < 64) atomicAdd(&outsums[tid], ls[tid]);
}

// ---------------- prep1: bn1 scale/shift + folded P/Q weights ----------------
__global__ __launch_bounds__(256) void k_prep1(
    const float* __restrict__ par, const float* __restrict__ stats,
    float* __restrict__ scale1, float* __restrict__ shift1,
    float* __restrict__ WP, float* __restrict__ WQ,
    float* __restrict__ bP, float* __restrict__ bQ)
{
    __shared__ float ssc[32], ssh[32];
    int tid = threadIdx.x;
    if (tid < 32) {
        float mu  = stats[tid] * (1.0f / NN);
        float var = stats[32 + tid] * (1.0f / NN) - mu * mu;
        float s   = par[O_GALL + tid] * rsqrtf(var + 1e-5f);
        float sh  = par[O_BEALL + tid] - mu * s;
        ssc[tid] = s; ssh[tid] = sh;
        scale1[tid] = s; shift1[tid] = sh;
    }
    __syncthreads();
    for (int e = tid; e < 1024; e += 256) {
        int k = e >> 5;
        float w1 = par[O_WMSG + e];
        float w2 = par[O_WMSG + 1024 + e];
        WP[e] = ssc[k] * (w1 - w2);
        WQ[e] = ssc[k] * w2;
    }
    if (tid < 32) {
        float aP = par[O_BMSG + tid], aQ = 0.0f;
        for (int k = 0; k < 32; k++) {
            float w1 = par[O_WMSG + k*32 + tid];
            float w2 = par[O_WMSG + (k+32)*32 + tid];
            aP += ssh[k] * (w1 - w2);
            aQ += ssh[k] * w2;
        }
        bP[tid] = aP; bQ[tid] = aQ;
    }
}

// ---------------- normalized emb + P' and Q per node ----------------
__global__ __launch_bounds__(256) void k_pq(
    const float* __restrict__ scale1, const float* __restrict__ shift1,
    const float* __restrict__ WP, const float* __restrict__ WQ,
    const float* __restrict__ bP, const float* __restrict__ bQ,
    float* __restrict__ emb, float* __restrict__ P, float* __restrict__ Q)
{
    __shared__ float sWP[1024], sWQ[1024], sbP[32], sbQ[32], ssc[32], ssh[32];
    int tid = threadIdx.x;
    for (int i = tid; i < 1024; i += 256) { sWP[i] = WP[i]; sWQ[i] = WQ[i]; }
    if (tid < 32) { sbP[tid] = bP[tid]; sbQ[tid] = bQ[tid]; ssc[tid] = scale1[tid]; ssh[tid] = shift1[tid]; }
    __syncthreads();

    int n = blockIdx.x * 256 + tid;
    if (n >= NN) return;

    float e[32];
    float4* er = (float4*)(emb + (size_t)n * 32);
    #pragma unroll
    for (int g = 0; g < 8; g++) {
        float4 v = er[g];
        e[g*4+0] = v.x; e[g*4+1] = v.y; e[g*4+2] = v.z; e[g*4+3] = v.w;
    }
    #pragma unroll
    for (int g = 0; g < 8; g++) {
        float4 v;
        v.x = e[g*4+0]*ssc[g*4+0] + ssh[g*4+0];
        v.y = e[g*4+1]*ssc[g*4+1] + ssh[g*4+1];
        v.z = e[g*4+2]*ssc[g*4+2] + ssh[g*4+2];
        v.w = e[g*4+3]*ssc[g*4+3] + ssh[g*4+3];
        er[g] = v;
    }
    float4* pr = (float4*)(P + (size_t)n * 32);
    float4* qr = (float4*)(Q + (size_t)n * 32);
    #pragma unroll
    for (int cg = 0; cg < 8; cg++) {
        float4 aP = *(const float4*)&sbP[cg*4];
        float4 aQ = *(const float4*)&sbQ[cg*4];
        #pragma unroll
        for (int k = 0; k < 32; k++) {
            float ek = e[k];
            float4 wp = *(const float4*)&sWP[k*32 + cg*4];
            float4 wq = *(const float4*)&sWQ[k*32 + cg*4];
            aP.x += ek * wp.x; aP.y += ek * wp.y; aP.z += ek * wp.z; aP.w += ek * wp.w;
            aQ.x += ek * wq.x; aQ.y += ek * wq.y; aQ.z += ek * wq.z; aQ.w += ek * wq.w;
        }
        pr[cg] = aP;
        qr[cg] = aQ;
    }
}

// ---------------- CSR build: histogram of dst ----------------
__global__ __launch_bounds__(256) void k_hist(const int* __restrict__ eidx,
                                              int* __restrict__ deg)
{
    int e4 = blockIdx.x * 256 + threadIdx.x;
    if (e4 >= EE / 4) return;
    const int4* dst4 = (const int4*)(eidx + EE);
    int4 d = dst4[e4];
    atomicAdd(&deg[d.x], 1);
    atomicAdd(&deg[d.y], 1);
    atomicAdd(&deg[d.z], 1);
    atomicAdd(&deg[d.w], 1);
}

// ---------------- CSR build: per-chunk exclusive scan ----------------
__global__ __launch_bounds__(256) void k_scanA(const int* __restrict__ deg,
                                               int* __restrict__ rowp,
                                               int* __restrict__ bsum)
{
    __shared__ int s[256];
    int tid = threadIdx.x;
    int i = blockIdx.x * 256 + tid;
    int v = (i < NN) ? deg[i] : 0;
    s[tid] = v;
    __syncthreads();
    for (int off = 1; off < 256; off <<= 1) {
        int x = (tid >= off) ? s[tid - off] : 0;
        __syncthreads();
        s[tid] += x;
        __syncthreads();
    }
    if (i < NN) rowp[i] = s[tid] - v;
    if (tid == 255) bsum[blockIdx.x] = s[255];
}

// ---------------- CSR build: scan of block sums (single block) ----------------
__global__ __launch_bounds__(512) void k_scanB(int* __restrict__ bsum)
{
    __shared__ int s[512];
    int tid = threadIdx.x;
    int v = (tid < NB_SCAN) ? bsum[tid] : 0;
    s[tid] = v;
    __syncthreads();
    for (int off = 1; off < 512; off <<= 1) {
        int x = (tid >= off) ? s[tid - off] : 0;
        __syncthreads();
        s[tid] += x;
        __syncthreads();
    }
    if (tid < NB_SCAN) bsum[tid] = s[tid] - v;   // exclusive
}

// ---------------- CSR build: add block offsets, init cursors ----------------
__global__ __launch_bounds__(256) void k_scanC(int* __restrict__ rowp,
                                               const int* __restrict__ bsum,
                                               int* __restrict__ curs)
{
    int tid = threadIdx.x;
    int i = blockIdx.x * 256 + tid;
    if (i < NN) {
        int r = rowp[i] + bsum[blockIdx.x];
        rowp[i] = r;
        curs[i] = r;
    }
    if (i == 0) rowp[NN] = EE;
}

// ---------------- CSR build: scatter src into dst-sorted order ----------------
__global__ __launch_bounds__(256) void k_scatter(const int* __restrict__ eidx,
                                                 int* __restrict__ curs,
                                                 int* __restrict__ srcl)
{
    int e4 = blockIdx.x * 256 + threadIdx.x;
    if (e4 >= EE / 4) return;
    const int4* src4 = (const int4*)eidx;
    const int4* dst4 = (const int4*)(eidx + EE);
    int4 s = src4[e4];
    int4 d = dst4[e4];
    int p0 = atomicAdd(&curs[d.x], 1); srcl[p0] = s.x;
    int p1 = atomicAdd(&curs[d.y], 1); srcl[p1] = s.y;
    int p2 = atomicAdd(&curs[d.z], 1); srcl[p2] = s.z;
    int p3 = atomicAdd(&curs[d.w], 1); srcl[p3] = s.w;
}

// ---------------- gather-max: agg[n] = deg>0 ? P[n] + max_{s in adj(n)} Q[s] : 0 ----------------
__global__ __launch_bounds__(256) void k_gather(
    const int* __restrict__ rowp, const int* __restrict__ srcl,
    const float* __restrict__ Q, const float* __restrict__ P,
    float* __restrict__ agg)
{
    int tid = threadIdx.x;
    int group = tid >> 3;        // 32 nodes per block
    int lane8 = tid & 7;         // float4 channel group
    int n = blockIdx.x * 32 + group;
    if (n >= NN) return;
    int beg = rowp[n], end = rowp[n + 1];
    const float4* Q4 = (const float4*)Q;
    float4 m = make_float4(-INFINITY, -INFINITY, -INFINITY, -INFINITY);
    for (int e = beg; e < end; e++) {
        int s = srcl[e];
        float4 q = Q4[(size_t)s * 8 + lane8];
        m.x = fmaxf(m.x, q.x); m.y = fmaxf(m.y, q.y);
        m.z = fmaxf(m.z, q.z); m.w = fmaxf(m.w, q.w);
    }
    float4 o;
    if (end > beg) {
        float4 p = ((const float4*)P)[(size_t)n * 8 + lane8];
        o = make_float4(m.x + p.x, m.y + p.y, m.z + p.z, m.w + p.w);
    } else {
        o = make_float4(0.f, 0.f, 0.f, 0.f);
    }
    ((float4*)agg)[(size_t)n * 8 + lane8] = o;
}

// ---------------- prep2: bn2 scale/shift ----------------
__global__ __launch_bounds__(64) void k_prep2(
    const float* __restrict__ par, const float* __restrict__ stats2,
    float* __restrict__ scale2, float* __restrict__ shift2)
{
    int c = threadIdx.x;
    if (c >= 32) return;
    float mu  = stats2[c] * (1.0f / NN);
    float var = stats2[32 + c] * (1.0f / NN) - mu * mu;
    float s   = par[O_GCONV + c] * rsqrtf(var + 1e-5f);
    scale2[c] = s;
    shift2[c] = par[O_BECONV + c] - mu * s;
}

// ---------------- output MLP ----------------
__global__ __launch_bounds__(256) void k_out(
    const float* __restrict__ emb, const float* __restrict__ agg,
    const float* __restrict__ scale2, const float* __restrict__ shift2,
    const float* __restrict__ par, const int* __restrict__ flag,
    void* __restrict__ out)
{
    __shared__ float sW1[512], sb1[16], sW2[16], ssc[32], ssh[32];
    __shared__ float sb2;
    int tid = threadIdx.x;
    for (int i = tid; i < 512; i += 256) sW1[i] = par[O_WOUT1 + i];
    if (tid < 16) { sb1[tid] = par[O_BOUT1 + tid]; sW2[tid] = par[O_WOUT2 + tid]; }
    if (tid < 32) { ssc[tid] = scale2[tid]; ssh[tid] = shift2[tid]; }
    if (tid == 0) sb2 = par[O_BOUT2];
    __syncthreads();

    int n = blockIdx.x * 256 + tid;
    if (n >= NN) return;

    const float4* er = (const float4*)(emb + (size_t)n * 32);
    const float4* ar = (const float4*)(agg + (size_t)n * 32);
    float h[32];
    #pragma unroll
    for (int g = 0; g < 8; g++) {
        float4 ev = er[g];
        float4 av = ar[g];
        h[g*4+0] = ev.x + av.x * ssc[g*4+0] + ssh[g*4+0];
        h[g*4+1] = ev.y + av.y * ssc[g*4+1] + ssh[g*4+1];
        h[g*4+2] = ev.z + av.z * ssc[g*4+2] + ssh[g*4+2];
        h[g*4+3] = ev.w + av.w * ssc[g*4+3] + ssh[g*4+3];
    }
    float o1[16];
    #pragma unroll
    for (int j = 0; j < 16; j++) {
        float a = sb1[j];
        #pragma unroll
        for (int k = 0; k < 32; k++) a += h[k] * sW1[k*16 + j];
        o1[j] = elu(a);
    }
    float acc = sb2;
    #pragma unroll
    for (int j = 0; j < 16; j++) acc += o1[j] * sW2[j];

    if (*flag) ((float*)out)[n] = acc;
    else       ((bf16_t*)out)[n] = __float2bfloat16(acc);
}

extern "C" void kernel_launch(void* const* d_in, const int* in_sizes, int n_in,
                              void* d_out, int out_size, void* d_ws, size_t ws_size,
                              hipStream_t stream)
{
    const int* x_cat = (const int*)d_in[1];
    const int* eidx  = (const int*)d_in[2];

    float* ws     = (float*)d_ws;
    float* fx     = ws + FX;
    float* par    = ws + PARB;
    float* emb    = ws + EMB;
    float* P      = ws + PBUF;
    float* Q      = ws + QBUF;
    float* agg    = ws + ABUF;
    float* stats  = ws + SOFF;            // [0:32) sum1 [32:64) sq1 [64:96) sum2 [96:128) sq2
    float* scale1 = stats + 128;
    float* shift1 = stats + 160;
    float* scale2 = stats + 192;
    float* shift2 = stats + 224;
    float* WP     = stats + 256;          // 1024
    float* WQ     = stats + 1280;         // 1024
    float* bP     = stats + 2304;         // 32
    float* bQ     = stats + 2336;         // 32
    int*   flag   = (int*)(stats + 2368);
    int*   deg    = (int*)(ws + DEG);
    int*   rowp   = (int*)(ws + ROWP);
    int*   curs   = (int*)(ws + CURS);
    int*   bsum   = (int*)(ws + BSUM);
    int*   srcl   = (int*)(ws + SRCL);

    hipMemsetAsync(stats, 0, 2376 * sizeof(float), stream);
    hipMemsetAsync(deg, 0, NN * sizeof(int), stream);

    k_detect<<<1, 64, 0, stream>>>((const unsigned short*)d_in[11], flag);

    ConvArgs ca;
    ca.xc = d_in[0];
    for (int t = 0; t < 19; t++) ca.p[t] = d_in[4 + t];
    ca.flag = flag; ca.fx = fx; ca.par = par;
    k_convert<<<587, 256, 0, stream>>>(ca);

    int nb = (NN + 255) / 256;  // 391
    // CSR build can run interleaved with the node pipeline (independent until k_gather)
    k_hist<<<(EE/4 + 255) / 256, 256, 0, stream>>>(eidx, deg);
    k_embed<<<nb, 256, 0, stream>>>(fx, x_cat, par, emb);
    k_scanA<<<NB_SCAN, 256, 0, stream>>>(deg, rowp, bsum);
    k_scanB<<<1, 512, 0, stream>>>(bsum);
    k_scanC<<<NB_SCAN, 256, 0, stream>>>(rowp, bsum, curs);
    k_scatter<<<(EE/4 + 255) / 256, 256, 0, stream>>>(eidx, curs, srcl);
    k_stats<<<512, 256, 0, stream>>>(emb, stats, NN * 32);
    k_prep1<<<1, 256, 0, stream>>>(par, stats, scale1, shift1, WP, WQ, bP, bQ);
    k_pq<<<nb, 256, 0, stream>>>(scale1, shift1, WP, WQ, bP, bQ, emb, P, Q);
    k_gather<<<(NN + 31) / 32, 256, 0, stream>>>(rowp, srcl, Q, P, agg);
    k_stats<<<512, 256, 0, stream>>>(agg, stats + 64, NN * 32);
    k_prep2<<<1, 64, 0, stream>>>(par, stats + 64, scale2, shift2);
    k_out<<<nb, 256, 0, stream>>>(emb, agg, scale2, shift2, par, flag, d_out);
}